// Round 6
// baseline (220.185 us; speedup 1.0000x reference)
//
#include <hip/hip_runtime.h>
#include <cstdint>

// CTC loss, tf.nn.ctc_loss semantics (blank_index=0), B=1024 T=256 C=128 L=32.
// One block (256 thr) per batch element, fused gather + alpha-DP.
//
// Round-6: the R1-R5 plateau (~95us fused / ~85us split) was Little's-law
// MLP starvation: VGPR_Count=52 => ~2-3 float4 in flight/wave => ~2 KB/CU
// outstanding => ~2.3 B/cy vs the ~7 KB needed for 6.3 TB/s. Fixes:
//  1. float4 v[2][8] explicit batch + double buffer: 8-16 loads in flight
//     per wave (launch_bounds(256,4) => 128 VGPR budget).
//  2. Gc in fp16 (log2 domain): LDS 17 KB.
//  3. DP LDS prefetch depth 4 (rolling regs, unroll 4) to cover ~120cy
//     ds_read latency.

#define CTC_BLANK 0
#define CTC_PAD   127
#define NEG       (-1e30f)
#define LOG2E     1.44269504088896340736f
#define LN2       0.69314718055994530942f

constexpr int Bn = 1024, Tn = 256, Cn = 128, Ln = 32;
constexpr int NSLOT = Ln + 1;   // 33: blank + up to 32 distinct labels
constexpr int PF = 4;           // DP prefetch depth

__device__ __forceinline__ float fexp2(float x) { return __builtin_amdgcn_exp2f(x); }
__device__ __forceinline__ float flog2(float x) { return __builtin_amdgcn_logf(x); }

// s += dpp_shift(s); invalid source lanes contribute 0 (bound_ctrl:0).
template <int CTRL>
__device__ __forceinline__ float dpp_add(float s) {
    int v = __builtin_amdgcn_update_dpp(0, __float_as_int(s), CTRL, 0xF, 0xF, true);
    return s + __int_as_float(v);
}
// lane i <- src[lane i-1]; lane 0 <- old.  (wave_shr:1, VALU pipe)
__device__ __forceinline__ float dpp_wave_shr1(float src, float old) {
    return __int_as_float(__builtin_amdgcn_update_dpp(
        __float_as_int(old), __float_as_int(src), 0x138, 0xF, 0xF, false));
}

__global__ __launch_bounds__(256, 4) void ctc_fused_kernel(
        const int*   __restrict__ y_true,   // [B, L]
        const float* __restrict__ y_pred,   // [B, T, C]
        float*       __restrict__ out)      // [B]
{
    __shared__ _Float16 Gc[Tn * NSLOT];      // log2-domain gathered logits, 16.9 KB
    __shared__ int   labels[Ln];
    __shared__ __align__(16) int cmap[Cn];   // class -> slot, -1 if unused
    __shared__ int   used[Cn];
    __shared__ int   wcnt[4];
    __shared__ float partS[8];

    const int b    = blockIdx.x;
    const int tid  = threadIdx.x;
    const int lane = tid & 63;
    const int wave = tid >> 6;

    // ---- class->slot map ----
    if (tid < Ln) labels[tid] = y_true[b * Ln + tid];
    if (tid < Cn) used[tid] = 0;
    __syncthreads();
    if (tid == 0) used[CTC_BLANK] = 1;
    if (tid < Ln) used[labels[tid]] = 1;   // racy same-value writes: fine
    __syncthreads();
    {
        bool f = (tid < Cn) && (used[tid] != 0);
        unsigned long long m = __ballot(f);
        if (lane == 0) wcnt[wave] = __popcll(m);
        __syncthreads();
        int base = 0;
        for (int w = 0; w < wave; ++w) base += wcnt[w];
        if (tid < Cn)
            cmap[tid] = f ? (base + __popcll(m & ((1ull << lane) - 1ull))) : -1;
        __syncthreads();
    }

    // ---- phase 1: batched loads (double-buffered) + gather + lse ----
    // Wave 'wave' covers rows [(wave*4+g)*16, +16) per group g; within a
    // group, lanes 0-31 row r (full 128 classes via float4), lanes 32-63
    // row r+1.  8 loads issued back-to-back per group => 8-16 float4 in
    // flight per wave continuously.
    const float* rowbase = y_pred + (size_t)b * Tn * Cn;
    const int half = lane >> 5;
    const int l32  = lane & 31;
    const int4 cm  = ((const int4*)cmap)[l32];
    float acc = 0.f;

    float4 v[2][8];
    #pragma unroll
    for (int j = 0; j < 8; ++j) {
        const int r = (wave * 4 + 0) * 16 + j * 2 + half;
        v[0][j] = ((const float4*)(rowbase + r * Cn))[l32];
    }
    for (int g = 0; g < 4; ++g) {
        if (g < 3) {
            #pragma unroll
            for (int j = 0; j < 8; ++j) {
                const int r = (wave * 4 + g + 1) * 16 + j * 2 + half;
                v[(g + 1) & 1][j] = ((const float4*)(rowbase + r * Cn))[l32];
            }
        }
        #pragma unroll
        for (int j = 0; j < 8; ++j) {
            const float4 x = v[g & 1][j];
            const int r = (wave * 4 + g) * 16 + j * 2 + half;
            if (cm.x >= 0) Gc[r * NSLOT + cm.x] = (_Float16)(x.x * LOG2E);
            if (cm.y >= 0) Gc[r * NSLOT + cm.y] = (_Float16)(x.y * LOG2E);
            if (cm.z >= 0) Gc[r * NSLOT + cm.z] = (_Float16)(x.z * LOG2E);
            if (cm.w >= 0) Gc[r * NSLOT + cm.w] = (_Float16)(x.w * LOG2E);
            float s = __expf(x.x) + __expf(x.y) + __expf(x.z) + __expf(x.w);
            s = dpp_add<0x111>(s);   // row_shr:1
            s = dpp_add<0x112>(s);   // row_shr:2
            s = dpp_add<0x114>(s);   // row_shr:4
            s = dpp_add<0x118>(s);   // row_shr:8
            s = dpp_add<0x142>(s);   // row_bcast:15
            acc += __logf(s);        // meaningful on lanes 31 / 63
        }
    }
    if (l32 == 31) partS[wave * 2 + half] = acc;
    __syncthreads();

    // ---- phase 2: alpha DP on wave 0 (log2 domain), prefetch depth 4 ----
    if (wave == 0) {
        const int i = lane;                       // lane i: states 2i, 2i+1
        const bool validO = (i < Ln);
        const bool validE = (i <= Ln);
        const int  myLab   = validO ? labels[i] : -1;
        const int  prevLab = (i >= 1 && i < Ln) ? labels[i - 1] : -1;
        const int  slotO   = validO ? cmap[myLab] : 0;
        const bool skipO   = (i >= 1 && i < Ln) &&
                             (myLab != CTC_BLANK) && (myLab != prevLab);
        const int  len = __popcll(__ballot(validO && (myLab != CTC_PAD)));

        float aE = (i == 0) ? (float)Gc[0]     : NEG;
        float aO = (i == 0) ? (float)Gc[slotO] : NEG;

        float pB[PF], pO[PF];
        #pragma unroll
        for (int j = 0; j < PF; ++j) {
            const int tj = 1 + j;
            pB[j] = (float)Gc[tj * NSLOT];
            pO[j] = (float)Gc[tj * NSLOT + slotO];
        }
        #pragma unroll 4
        for (int t = 1; t < Tn; ++t) {
            const float lpB = pB[0], lpO = pO[0];
            #pragma unroll
            for (int j = 0; j < PF - 1; ++j) { pB[j] = pB[j + 1]; pO[j] = pO[j + 1]; }
            const int tn = (t + PF < Tn) ? t + PF : Tn - 1;
            pB[PF - 1] = (float)Gc[tn * NSLOT];
            pO[PF - 1] = (float)Gc[tn * NSLOT + slotO];

            const float aOup = dpp_wave_shr1(aO, NEG);   // alpha[2i-1]
            const float m  = fmaxf(aE, aOup);
            const float e1 = fexp2(aE - m);
            const float e2 = fexp2(aOup - m);
            const float sE = e1 + e2;
            const float nE = lpB + m + flog2(sE);                // s = 2i
            const float m3 = fmaxf(aO, m);
            const float nO = lpO + m3 +                          // s = 2i+1
                flog2(fexp2(aO - m3) + (skipO ? sE : e1) * fexp2(m - m3));
            aE = validE ? nE : NEG;
            aO = validO ? nO : NEG;
        }

        const float v1 = __shfl(aE, len, 64);       // alpha[2*len]
        const float v2 = __shfl(aO, len - 1, 64);   // alpha[2*len-1]
        if (i == 0) {
            const float S = partS[0] + partS[1] + partS[2] + partS[3] +
                            partS[4] + partS[5] + partS[6] + partS[7];
            const float mm = fmaxf(v1, v2);
            const float L2 = mm + flog2(fexp2(v1 - mm) + fexp2(v2 - mm));
            out[b] = S - LN2 * L2;   // S is natural-log lse sum; L2 log2-domain
        }
    }
}

extern "C" void kernel_launch(void* const* d_in, const int* in_sizes, int n_in,
                              void* d_out, int out_size, void* d_ws, size_t ws_size,
                              hipStream_t stream) {
    const int*   y_true = (const int*)d_in[0];
    const float* y_pred = (const float*)d_in[1];
    float*       out    = (float*)d_out;
    ctc_fused_kernel<<<Bn, 256, 0, stream>>>(y_true, y_pred, out);
}

// Round 7
// 209.285 us; speedup vs baseline: 1.0521x; 1.0521x over previous
//
#include <hip/hip_runtime.h>
#include <cstdint>

// CTC loss, tf.nn.ctc_loss semantics (blank_index=0), B=1024 T=256 C=128 L=32.
// One block (512 thr = 8 waves) per batch element, fused gather + alpha-DP.
//
// Round-7: R6 counters (VGPR=56) showed the compiler collapsed the explicit
// double buffer -> ~8 loads in flight/wave; at 16 waves/CU that's 2 KB/CU
// outstanding = ~1.5 TB/s (matches 128MB/84.5us measured). Fix the OTHER
// Little's-law factor: waves/CU.
//  1. 8-wave blocks + __launch_bounds__(512,8): 32 waves/CU (100% occ),
//     VGPR forced <=64 so it's reachable. ~4 KB/CU in flight -> ~2x BW.
//  2. DP overlapped with staging: 2 chunks x 128 rows; wave 0 runs DP of
//     chunk c-1 while all waves stage chunk c (barrier per chunk). Exposed
//     DP = last 128 steps only.
//  3. Gc fp16 log2-domain (18 KB LDS), PF=2 rolling prefetch in DP.

#define CTC_BLANK 0
#define CTC_PAD   127
#define NEG       (-1e30f)
#define LOG2E     1.44269504088896340736f
#define LN2       0.69314718055994530942f

constexpr int Bn = 1024, Tn = 256, Cn = 128, Ln = 32;
constexpr int NSLOT = Ln + 1;   // 33: blank + up to 32 distinct labels
constexpr int NCH = 2;          // staging chunks
constexpr int CR  = Tn / NCH;   // 128 rows per chunk

__device__ __forceinline__ float fexp2(float x) { return __builtin_amdgcn_exp2f(x); }
__device__ __forceinline__ float flog2(float x) { return __builtin_amdgcn_logf(x); }

// s += dpp_shift(s); invalid source lanes contribute 0 (bound_ctrl:0).
template <int CTRL>
__device__ __forceinline__ float dpp_add(float s) {
    int v = __builtin_amdgcn_update_dpp(0, __float_as_int(s), CTRL, 0xF, 0xF, true);
    return s + __int_as_float(v);
}
// lane i <- src[lane i-1]; lane 0 <- old.  (wave_shr:1, VALU pipe)
__device__ __forceinline__ float dpp_wave_shr1(float src, float old) {
    return __int_as_float(__builtin_amdgcn_update_dpp(
        __float_as_int(old), __float_as_int(src), 0x138, 0xF, 0xF, false));
}

__global__ __launch_bounds__(512, 8) void ctc_fused_kernel(
        const int*   __restrict__ y_true,   // [B, L]
        const float* __restrict__ y_pred,   // [B, T, C]
        float*       __restrict__ out)      // [B]
{
    __shared__ _Float16 Gc[Tn * NSLOT];      // log2-domain gathered logits, 16.9 KB
    __shared__ int   labels[Ln];
    __shared__ __align__(16) int cmap[Cn];   // class -> slot, -1 if unused
    __shared__ int   used[Cn];
    __shared__ int   wcnt[8];
    __shared__ float partS[16];

    const int b    = blockIdx.x;
    const int tid  = threadIdx.x;
    const int lane = tid & 63;
    const int wave = tid >> 6;

    // ---- class->slot map (waves 0-1 cover the 128 classes) ----
    if (tid < Ln) labels[tid] = y_true[b * Ln + tid];
    if (tid < Cn) used[tid] = 0;
    __syncthreads();
    if (tid == 0) used[CTC_BLANK] = 1;
    if (tid < Ln) used[labels[tid]] = 1;   // racy same-value writes: fine
    __syncthreads();
    {
        bool f = (tid < Cn) && (used[tid] != 0);
        unsigned long long m = __ballot(f);
        if (lane == 0) wcnt[wave] = __popcll(m);
        __syncthreads();
        int base = 0;
        for (int w = 0; w < wave; ++w) base += wcnt[w];
        if (tid < Cn)
            cmap[tid] = f ? (base + __popcll(m & ((1ull << lane) - 1ull))) : -1;
        __syncthreads();
    }

    // ---- per-thread staging constants ----
    const float* rowbase = y_pred + (size_t)b * Tn * Cn;
    const int half = lane >> 5;
    const int l32  = lane & 31;
    const int4 cm  = ((const int4*)cmap)[l32];
    float acc = 0.f;

    // ---- DP constants (identical on every wave; only wave 0 uses them) ----
    const int  i      = lane;                 // lane i: states 2i, 2i+1
    const bool validO = (i < Ln);
    const bool validE = (i <= Ln);
    const int  myLab   = validO ? labels[i] : -1;
    const int  prevLab = (i >= 1 && i < Ln) ? labels[i - 1] : -1;
    const int  slotO   = validO ? cmap[myLab] : 0;
    const bool skipO   = (i >= 1 && i < Ln) &&
                         (myLab != CTC_BLANK) && (myLab != prevLab);
    const int  len = __popcll(__ballot(validO && (myLab != CTC_PAD)));
    float aE = NEG, aO = NEG;                 // persistent DP state

    // DP over rows [t0, t1) of Gc (log2 domain), PF=2 rolling prefetch.
    // Prefetch clamped to t1-1: never reads rows of a chunk still being staged.
    auto dp_chunk = [&](int t0, int t1) {
        int t = t0;
        if (t == 0) {
            aE = (i == 0) ? (float)Gc[0]     : NEG;
            aO = (i == 0) ? (float)Gc[slotO] : NEG;
            t = 1;
        }
        float pB[2], pO[2];
        const int ta = t, tb = (t + 1 < t1) ? t + 1 : t1 - 1;
        pB[0] = (float)Gc[ta * NSLOT]; pO[0] = (float)Gc[ta * NSLOT + slotO];
        pB[1] = (float)Gc[tb * NSLOT]; pO[1] = (float)Gc[tb * NSLOT + slotO];
        int k = 0;
        #pragma unroll 2
        for (; t < t1; ++t) {
            const float lpB = pB[k], lpO = pO[k];
            const int tp = (t + 2 < t1) ? t + 2 : t1 - 1;
            pB[k] = (float)Gc[tp * NSLOT];
            pO[k] = (float)Gc[tp * NSLOT + slotO];
            k ^= 1;

            const float aOup = dpp_wave_shr1(aO, NEG);   // alpha[2i-1]
            const float m  = fmaxf(aE, aOup);
            const float e1 = fexp2(aE - m);
            const float e2 = fexp2(aOup - m);
            const float sE = e1 + e2;
            const float nE = lpB + m + flog2(sE);                // s = 2i
            const float m3 = fmaxf(aO, m);
            const float nO = lpO + m3 +                          // s = 2i+1
                flog2(fexp2(aO - m3) + (skipO ? sE : e1) * fexp2(m - m3));
            aE = validE ? nE : NEG;
            aO = validO ? nO : NEG;
        }
    };

    // ---- chunked staging with DP overlap ----
    // Chunk c: each wave stages 8 row-pairs (8 float4 loads in flight).
    for (int c = 0; c < NCH; ++c) {
        if (wave == 0 && c > 0) dp_chunk((c - 1) * CR, c * CR);

        const int cbase = c * CR;
        float4 v[8];
        #pragma unroll
        for (int j = 0; j < 8; ++j) {
            const int r = cbase + 2 * (wave * 8 + j) + half;
            v[j] = ((const float4*)(rowbase + r * Cn))[l32];
        }
        #pragma unroll
        for (int j = 0; j < 8; ++j) {
            const int r = cbase + 2 * (wave * 8 + j) + half;
            const float4 x = v[j];
            if (cm.x >= 0) Gc[r * NSLOT + cm.x] = (_Float16)(x.x * LOG2E);
            if (cm.y >= 0) Gc[r * NSLOT + cm.y] = (_Float16)(x.y * LOG2E);
            if (cm.z >= 0) Gc[r * NSLOT + cm.z] = (_Float16)(x.z * LOG2E);
            if (cm.w >= 0) Gc[r * NSLOT + cm.w] = (_Float16)(x.w * LOG2E);
            float s = __expf(x.x) + __expf(x.y) + __expf(x.z) + __expf(x.w);
            s = dpp_add<0x111>(s);   // row_shr:1
            s = dpp_add<0x112>(s);   // row_shr:2
            s = dpp_add<0x114>(s);   // row_shr:4
            s = dpp_add<0x118>(s);   // row_shr:8
            s = dpp_add<0x142>(s);   // row_bcast:15
            acc += __logf(s);        // valid on lanes 31 / 63
        }
        if (c == NCH - 1 && l32 == 31) partS[wave * 2 + half] = acc;
        __syncthreads();
    }

    // ---- final DP chunk + epilogue (wave 0) ----
    if (wave == 0) {
        dp_chunk((NCH - 1) * CR, Tn);
        const float v1 = __shfl(aE, len, 64);       // alpha[2*len]
        const float v2 = __shfl(aO, len - 1, 64);   // alpha[2*len-1]
        if (i == 0) {
            float S = 0.f;
            #pragma unroll
            for (int j = 0; j < 16; ++j) S += partS[j];
            const float mm = fmaxf(v1, v2);
            const float L2 = mm + flog2(fexp2(v1 - mm) + fexp2(v2 - mm));
            out[b] = S - LN2 * L2;   // S: natural-log lse sum; L2: log2 domain
        }
    }
}

extern "C" void kernel_launch(void* const* d_in, const int* in_sizes, int n_in,
                              void* d_out, int out_size, void* d_ws, size_t ws_size,
                              hipStream_t stream) {
    const int*   y_true = (const int*)d_in[0];
    const float* y_pred = (const float*)d_in[1];
    float*       out    = (float*)d_out;
    ctc_fused_kernel<<<Bn, 512, 0, stream>>>(y_true, y_pred, out);
}

// Round 8
// 206.746 us; speedup vs baseline: 1.0650x; 1.0123x over previous
//
#include <hip/hip_runtime.h>
#include <cstdint>

// CTC loss, tf.nn.ctc_loss semantics (blank_index=0), B=1024 T=256 C=128 L=32.
// One block (512 thr = 8 waves) per batch element.
//
// Round-8: R6/R7 proved the register allocator always collapses VGPR-held
// load batches (VGPR 56 -> 28 when occupancy was raised), capping in-flight
// bytes. Switch staging to __builtin_amdgcn_global_load_lds (width 16):
// VGPR-free, queue-limited MLP. 16-row (8 KB) chunks, double-buffered raw
// LDS; each wave issues ONE direct-to-LDS instruction per chunk (layout =
// natural linear order, satisfying the wave-uniform-base + lane*16 rule).
// Softmax/gather read raw rows from LDS; wave 0 runs the alpha-DP lagging
// one chunk behind. LDS 34.5 KB -> 4 blocks/CU (32 waves, 100% occ).

#define CTC_BLANK 0
#define CTC_PAD   127
#define NEG       (-1e30f)
#define LOG2E     1.44269504088896340736f
#define LN2       0.69314718055994530942f

constexpr int Bn = 1024, Tn = 256, Cn = 128, Ln = 32;
constexpr int NSLOT = Ln + 1;     // 33: blank + up to 32 distinct labels
constexpr int CR  = 16;           // rows per chunk
constexpr int NCH = Tn / CR;      // 16 chunks
constexpr int CF  = CR * Cn;      // 2048 floats per chunk (8 KB)

__device__ __forceinline__ float fexp2(float x) { return __builtin_amdgcn_exp2f(x); }
__device__ __forceinline__ float flog2(float x) { return __builtin_amdgcn_logf(x); }

// s += dpp_shift(s); invalid source lanes contribute 0 (bound_ctrl:0).
template <int CTRL>
__device__ __forceinline__ float dpp_add(float s) {
    int v = __builtin_amdgcn_update_dpp(0, __float_as_int(s), CTRL, 0xF, 0xF, true);
    return s + __int_as_float(v);
}
// lane i <- src[lane i-1]; lane 0 <- old.  (wave_shr:1, VALU pipe)
__device__ __forceinline__ float dpp_wave_shr1(float src, float old) {
    return __int_as_float(__builtin_amdgcn_update_dpp(
        __float_as_int(old), __float_as_int(src), 0x138, 0xF, 0xF, false));
}
// async global->LDS, 16 B/lane; lptr must be wave-uniform (lane lands at
// lptr + lane*16).
__device__ __forceinline__ void gl_lds16(const float* g, float* l) {
    __builtin_amdgcn_global_load_lds(
        (const __attribute__((address_space(1))) uint32_t*)g,
        (__attribute__((address_space(3))) uint32_t*)l, 16, 0, 0);
}

__global__ __launch_bounds__(512, 8) void ctc_fused_kernel(
        const int*   __restrict__ y_true,   // [B, L]
        const float* __restrict__ y_pred,   // [B, T, C]
        float*       __restrict__ out)      // [B]
{
    __shared__ __align__(16) float raw[2][CF];     // 16 KB raw logit chunks
    __shared__ _Float16 Gc[Tn * NSLOT];            // 16.9 KB, log2-domain
    __shared__ int   labels[Ln];
    __shared__ __align__(16) int cmap[Cn];
    __shared__ int   used[Cn];
    __shared__ int   wcnt[8];
    __shared__ float partS[16];

    const int b    = blockIdx.x;
    const int tid  = threadIdx.x;
    const int lane = tid & 63;
    const int wave = tid >> 6;

    const float* gbase = y_pred + (size_t)b * Tn * Cn;

    // issue chunk c into raw[buf]: one global_load_lds per wave
    auto stage = [&](int c, int buf) {
        gl_lds16(gbase + c * CF + tid * 4, &raw[buf][wave * 256]);
    };

    stage(0, 0);   // chunk-0 latency hides behind the cmap build below

    // ---- class->slot map ----
    if (tid < Ln) labels[tid] = y_true[b * Ln + tid];
    if (tid < Cn) used[tid] = 0;
    __syncthreads();
    if (tid == 0) used[CTC_BLANK] = 1;
    if (tid < Ln) used[labels[tid]] = 1;   // racy same-value writes: fine
    __syncthreads();
    {
        bool f = (tid < Cn) && (used[tid] != 0);
        unsigned long long m = __ballot(f);
        if (lane == 0) wcnt[wave] = __popcll(m);
        __syncthreads();
        int base = 0;
        for (int w = 0; w < wave; ++w) base += wcnt[w];
        if (tid < Cn)
            cmap[tid] = f ? (base + __popcll(m & ((1ull << lane) - 1ull))) : -1;
        __syncthreads();   // also drains chunk-0 global_load_lds
    }

    // ---- per-thread processing constants ----
    const int half = lane >> 5;
    const int l32  = lane & 31;
    const int4 cm  = ((const int4*)cmap)[l32];
    float acc = 0.f;

    // ---- DP constants (uniform across waves; only wave 0 runs DP) ----
    const int  i      = lane;                 // lane i: states 2i, 2i+1
    const bool validO = (i < Ln);
    const bool validE = (i <= Ln);
    const int  myLab   = validO ? labels[i] : -1;
    const int  prevLab = (i >= 1 && i < Ln) ? labels[i - 1] : -1;
    const int  slotO   = validO ? cmap[myLab] : 0;
    const bool skipO   = (i >= 1 && i < Ln) &&
                         (myLab != CTC_BLANK) && (myLab != prevLab);
    const int  len = __popcll(__ballot(validO && (myLab != CTC_PAD)));
    float aE = NEG, aO = NEG;

    auto dp_chunk = [&](int t0, int t1) {
        int t = t0;
        if (t == 0) {
            aE = (i == 0) ? (float)Gc[0]     : NEG;
            aO = (i == 0) ? (float)Gc[slotO] : NEG;
            t = 1;
        }
        float pB[2], pO[2];
        const int ta = t, tb = (t + 1 < t1) ? t + 1 : t1 - 1;
        pB[0] = (float)Gc[ta * NSLOT]; pO[0] = (float)Gc[ta * NSLOT + slotO];
        pB[1] = (float)Gc[tb * NSLOT]; pO[1] = (float)Gc[tb * NSLOT + slotO];
        int k = 0;
        #pragma unroll 2
        for (; t < t1; ++t) {
            const float lpB = pB[k], lpO = pO[k];
            const int tp = (t + 2 < t1) ? t + 2 : t1 - 1;
            pB[k] = (float)Gc[tp * NSLOT];
            pO[k] = (float)Gc[tp * NSLOT + slotO];
            k ^= 1;

            const float aOup = dpp_wave_shr1(aO, NEG);   // alpha[2i-1]
            const float m  = fmaxf(aE, aOup);
            const float e1 = fexp2(aE - m);
            const float e2 = fexp2(aOup - m);
            const float sE = e1 + e2;
            const float nE = lpB + m + flog2(sE);                // s = 2i
            const float m3 = fmaxf(aO, m);
            const float nO = lpO + m3 +                          // s = 2i+1
                flog2(fexp2(aO - m3) + (skipO ? sE : e1) * fexp2(m - m3));
            aE = validE ? nE : NEG;
            aO = validO ? nO : NEG;
        }
    };

    // ---- pipelined: stage c+1 || process c || DP c-1 ----
    for (int c = 0; c < NCH; ++c) {
        if (c + 1 < NCH) stage(c + 1, (c + 1) & 1);

        // process chunk c: wave w handles rows 2w (lanes 0-31) / 2w+1 (32-63)
        {
            const int rl = 2 * wave + half;        // 0..15 within chunk
            const int r  = c * CR + rl;
            const float4 x = ((const float4*)&raw[c & 1][rl * Cn])[l32];
            if (cm.x >= 0) Gc[r * NSLOT + cm.x] = (_Float16)(x.x * LOG2E);
            if (cm.y >= 0) Gc[r * NSLOT + cm.y] = (_Float16)(x.y * LOG2E);
            if (cm.z >= 0) Gc[r * NSLOT + cm.z] = (_Float16)(x.z * LOG2E);
            if (cm.w >= 0) Gc[r * NSLOT + cm.w] = (_Float16)(x.w * LOG2E);
            float s = __expf(x.x) + __expf(x.y) + __expf(x.z) + __expf(x.w);
            s = dpp_add<0x111>(s);   // row_shr:1
            s = dpp_add<0x112>(s);   // row_shr:2
            s = dpp_add<0x114>(s);   // row_shr:4
            s = dpp_add<0x118>(s);   // row_shr:8
            s = dpp_add<0x142>(s);   // row_bcast:15
            acc += __logf(s);        // valid on lanes 31 / 63
        }

        if (wave == 0 && c > 0) dp_chunk((c - 1) * CR, c * CR);
        if (c == NCH - 1 && l32 == 31) partS[wave * 2 + half] = acc;
        __syncthreads();   // drains chunk c+1 loads; publishes Gc rows of c
    }

    // ---- final DP chunk + epilogue ----
    if (wave == 0) {
        dp_chunk(Tn - CR, Tn);
        const float v1 = __shfl(aE, len, 64);       // alpha[2*len]
        const float v2 = __shfl(aO, len - 1, 64);   // alpha[2*len-1]
        if (i == 0) {
            float S = 0.f;
            #pragma unroll
            for (int j = 0; j < 16; ++j) S += partS[j];
            const float mm = fmaxf(v1, v2);
            const float L2 = mm + flog2(fexp2(v1 - mm) + fexp2(v2 - mm));
            out[b] = S - LN2 * L2;   // S: natural-log lse sum; L2: log2 domain
        }
    }
}

extern "C" void kernel_launch(void* const* d_in, const int* in_sizes, int n_in,
                              void* d_out, int out_size, void* d_ws, size_t ws_size,
                              hipStream_t stream) {
    const int*   y_true = (const int*)d_in[0];
    const float* y_pred = (const float*)d_in[1];
    float*       out    = (float*)d_out;
    ctc_fused_kernel<<<Bn, 512, 0, stream>>>(y_true, y_pred, out);
}